// Round 1
// baseline (401.319 us; speedup 1.0000x reference)
//
#include <hip/hip_runtime.h>
#include <hip/hip_bf16.h>

// LiquidNet2: B=1024, I=128, S=512, UNFOLDS=6
// out v[B,S] fp32.
//
// Packed params (prep kernel): per (i,j): {A = -sigma*log2e, C = sigma*mu*log2e,
// Wn = W*erev, Wp = W}, so sig = 1/(1+exp2(A*v + C)), num += Wn*sig, den += Wp*sig.

#define B_TOT 1024
#define I_DIM 128
#define S_DIM 512
#define UNFOLDS 6
#define BT 4   // batches per block

#if __has_builtin(__builtin_amdgcn_exp2f)
__device__ __forceinline__ float fast_exp2(float x) { return __builtin_amdgcn_exp2f(x); }
#else
__device__ __forceinline__ float fast_exp2(float x) {
    float r; asm("v_exp_f32 %0, %1" : "=v"(r) : "v"(x)); return r;
}
#endif

#if __has_builtin(__builtin_amdgcn_rcpf)
__device__ __forceinline__ float fast_rcp(float x) { return __builtin_amdgcn_rcpf(x); }
#else
__device__ __forceinline__ float fast_rcp(float x) {
    float r; asm("v_rcp_f32 %0, %1" : "=v"(r) : "v"(x)); return r;
}
#endif

__global__ __launch_bounds__(256) void prep_kernel(
    const float* __restrict__ sens_mu, const float* __restrict__ sens_sigma,
    const float* __restrict__ sens_W, const float* __restrict__ sens_erev,
    const float* __restrict__ mu, const float* __restrict__ sigma,
    const float* __restrict__ W, const float* __restrict__ erev,
    float4* __restrict__ recP, float4* __restrict__ sensP)
{
    const float L2E = 1.4426950408889634f;
    int idx = blockIdx.x * 256 + threadIdx.x;
    if (idx < I_DIM * S_DIM) {
        float sg = sens_sigma[idx], m = sens_mu[idx], w = sens_W[idx], er = sens_erev[idx];
        sensP[idx] = make_float4(-sg * L2E, sg * m * L2E, w * er, w);
    }
    if (idx < S_DIM * S_DIM) {
        float sg = sigma[idx], m = mu[idx], w = W[idx], er = erev[idx];
        recP[idx] = make_float4(-sg * L2E, sg * m * L2E, w * er, w);
    }
}

__global__ __launch_bounds__(512, 2) void liquid_main(
    const float* __restrict__ inputs,   // [B, I]
    const float* __restrict__ hx,       // [B, S]
    const float* __restrict__ input_w,  // [I]
    const float* __restrict__ input_b,  // [I]
    const float4* __restrict__ sensP,   // [I*S]
    const float4* __restrict__ recP,    // [S*S]
    const float* __restrict__ vleak,    // [S]
    const float* __restrict__ gleak,    // [S]
    const float* __restrict__ cm_t,     // [S]
    float* __restrict__ out)            // [B, S]
{
    const int j = threadIdx.x;          // post neuron, 0..511
    const int b0 = blockIdx.x * BT;

    __shared__ float xs[BT][I_DIM];
    __shared__ float vs[BT][S_DIM];

    // stage x = inputs*w + b  (512 threads cover BT*128 = 512 elems)
    {
        int b = threadIdx.x >> 7, ii = threadIdx.x & 127;
        xs[b][ii] = inputs[(b0 + b) * I_DIM + ii] * input_w[ii] + input_b[ii];
    }
    #pragma unroll
    for (int k = 0; k < BT; ++k)
        vs[k][j] = hx[(b0 + k) * S_DIM + j];
    __syncthreads();

    // ---- sensory reduction (once) ----
    float snum[BT], sden[BT];
    #pragma unroll
    for (int b = 0; b < BT; ++b) { snum[b] = 0.f; sden[b] = 0.f; }

    for (int i = 0; i < I_DIM; i += 4) {
        float4 p[4];
        #pragma unroll
        for (int u = 0; u < 4; ++u) p[u] = sensP[(i + u) * S_DIM + j];
        #pragma unroll
        for (int b = 0; b < BT; ++b) {
            float4 xv4 = *(const float4*)&xs[b][i];
            float xv[4] = {xv4.x, xv4.y, xv4.z, xv4.w};
            #pragma unroll
            for (int u = 0; u < 4; ++u) {
                float t = fmaf(p[u].x, xv[u], p[u].y);
                float e = fast_exp2(t);
                float s = fast_rcp(1.0f + e);
                snum[b] = fmaf(p[u].z, s, snum[b]);
                sden[b] = fmaf(p[u].w, s, sden[b]);
            }
        }
    }

    const float gl = gleak[j], vl = vleak[j], cmj = cm_t[j];
    const float glvl = gl * vl;
    const float cg = cmj + gl;

    // ---- unfolds ----
    for (int it = 0; it < UNFOLDS; ++it) {
        float num[BT], den[BT];
        #pragma unroll
        for (int b = 0; b < BT; ++b) { num[b] = snum[b]; den[b] = sden[b]; }

        for (int i = 0; i < S_DIM; i += 4) {
            float4 p[4];
            #pragma unroll
            for (int u = 0; u < 4; ++u) p[u] = recP[(i + u) * S_DIM + j];
            #pragma unroll
            for (int b = 0; b < BT; ++b) {
                float4 vv4 = *(const float4*)&vs[b][i];
                float vv[4] = {vv4.x, vv4.y, vv4.z, vv4.w};
                #pragma unroll
                for (int u = 0; u < 4; ++u) {
                    float t = fmaf(p[u].x, vv[u], p[u].y);
                    float e = fast_exp2(t);
                    float s = fast_rcp(1.0f + e);
                    num[b] = fmaf(p[u].z, s, num[b]);
                    den[b] = fmaf(p[u].w, s, den[b]);
                }
            }
        }

        float vnew[BT];
        #pragma unroll
        for (int b = 0; b < BT; ++b) {
            float vold = vs[b][j];
            vnew[b] = (fmaf(cmj, vold, glvl) + num[b]) / (cg + den[b]);
        }
        __syncthreads();
        #pragma unroll
        for (int b = 0; b < BT; ++b) vs[b][j] = vnew[b];
        __syncthreads();
    }

    #pragma unroll
    for (int b = 0; b < BT; ++b)
        out[(b0 + b) * S_DIM + j] = vs[b][j];
}

extern "C" void kernel_launch(void* const* d_in, const int* in_sizes, int n_in,
                              void* d_out, int out_size, void* d_ws, size_t ws_size,
                              hipStream_t stream) {
    // setup_inputs order:
    // 0 inputs [B,I], 1 hx [B,S], 2 input_w [I], 3 input_b [I],
    // 4 sensory_mu [I,S], 5 sensory_sigma [I,S], 6 sensory_W [I,S], 7 sensory_erev [I,S],
    // 8 mu [S,S], 9 sigma [S,S], 10 W [S,S], 11 erev [S,S],
    // 12 vleak [S], 13 gleak [S], 14 cm_t [S]
    const float* inputs   = (const float*)d_in[0];
    const float* hx       = (const float*)d_in[1];
    const float* input_w  = (const float*)d_in[2];
    const float* input_b  = (const float*)d_in[3];
    const float* s_mu     = (const float*)d_in[4];
    const float* s_sigma  = (const float*)d_in[5];
    const float* s_W      = (const float*)d_in[6];
    const float* s_erev   = (const float*)d_in[7];
    const float* mu       = (const float*)d_in[8];
    const float* sigma    = (const float*)d_in[9];
    const float* W        = (const float*)d_in[10];
    const float* erev     = (const float*)d_in[11];
    const float* vleak    = (const float*)d_in[12];
    const float* gleak    = (const float*)d_in[13];
    const float* cm_t     = (const float*)d_in[14];
    float* out = (float*)d_out;

    // workspace layout: recP [S*S] float4 at 0 (4 MB), sensP [I*S] float4 after (1 MB)
    float4* recP  = (float4*)d_ws;
    float4* sensP = (float4*)((char*)d_ws + (size_t)S_DIM * S_DIM * sizeof(float4));

    int prep_threads = S_DIM * S_DIM;           // covers sensory too (I*S < S*S)
    prep_kernel<<<(prep_threads + 255) / 256, 256, 0, stream>>>(
        s_mu, s_sigma, s_W, s_erev, mu, sigma, W, erev, recP, sensP);

    liquid_main<<<B_TOT / BT, S_DIM, 0, stream>>>(
        inputs, hx, input_w, input_b, sensP, recP, vleak, gleak, cm_t, out);
}